// Round 2
// baseline (2095.175 us; speedup 1.0000x reference)
//
#include <hip/hip_runtime.h>
#include <hip/hip_bf16.h>

// DecoderRNN: emb gather+relu -> gi GEMM (hoisted) -> ONE persistent GRU kernel
// (64 steps, w_hh LDS/VGPR-resident, h-state register-resident, hand-rolled
// device-scope grid barrier between steps; NO cooperative launch) -> output
// projection GEMM (4096x32000x1024 bf16 MFMA, XCD-supertile-swizzled) with
// permuted (b,s,v) store + bias.
//
// Sizes: VOCAB=32000, EMB=512, HID=1024, SEQ=64, BATCH=64.

#define VOCAB 32000
#define EMB 512
#define HID 1024
#define SEQ 64
#define BATCH 64

typedef __bf16 bf16_8 __attribute__((ext_vector_type(8)));
typedef float f32x4 __attribute__((ext_vector_type(4)));

__device__ __forceinline__ unsigned short f32_to_bf16_rne(float f) {
    unsigned int u = __float_as_uint(f);
    u = (u + 0x7FFFu + ((u >> 16) & 1u)) >> 16;
    return (unsigned short)u;
}

__device__ __forceinline__ void gld_lds16(const unsigned short* g, unsigned short* l) {
    __builtin_amdgcn_global_load_lds(
        (__attribute__((address_space(1))) void*)g,
        (__attribute__((address_space(3))) void*)l, 16, 0, 0);
}

// ---------------- converters ----------------
__global__ void f32_to_bf16_vec(const float* __restrict__ in,
                                unsigned short* __restrict__ out, int n4) {
    int i = blockIdx.x * blockDim.x + threadIdx.x;
    if (i < n4) {
        float4 v = ((const float4*)in)[i];
        ushort4 o;
        o.x = f32_to_bf16_rne(v.x);
        o.y = f32_to_bf16_rne(v.y);
        o.z = f32_to_bf16_rne(v.z);
        o.w = f32_to_bf16_rne(v.w);
        ((ushort4*)out)[i] = o;
    }
}

// h0 -> bf16, and zero the grid-barrier region (fresh per graph replay)
__global__ void init_h_kernel(const float* __restrict__ h0,
                              unsigned short* __restrict__ hb0,
                              unsigned* __restrict__ bar) {
    int i = blockIdx.x * blockDim.x + threadIdx.x;  // 65536
    if (i < 4608) bar[i] = 0;                       // 256 slots*16 + flag
    hb0[i] = f32_to_bf16_rne(h0[i]);
}

// ---------------- embedding gather + relu -> bf16 ----------------
__global__ void embed_relu_kernel(const int* __restrict__ x,
                                  const float* __restrict__ emb,
                                  unsigned short* __restrict__ e_bf) {
    int idx = blockIdx.x * blockDim.x + threadIdx.x;  // 4096*512
    int row = idx >> 9;       // (s*64+b)
    int k = idx & 511;
    int s = row >> 6, b = row & 63;
    int tok = (s == 0) ? 2 : x[(s - 1) * 64 + b];
    float v = emb[(long)tok * EMB + k];
    v = v > 0.f ? v : 0.f;   // relu (also covers padding row 0, already zero)
    e_bf[idx] = f32_to_bf16_rne(v);
}

// ---------------- bf16 MFMA GEMM: C(M,N) = A(M,K) * B(N,K)^T + bias ----------------
// 128x128 block tile, BK=32, 4 waves (2x2), each wave 64x64 via 4x4 mfma_16x16x32.
// XCD swizzle: each XCD's chunk = 4 consecutive bm rows x all bn (cpx = 4*gridDim.x,
// exact at both call sites), walked in supertiles of 4 x sb tiles so the A row-panel
// (1MB) + sb B panels fit the XCD's 4MB L2.
// permute=0: C[r*N+c]; permute=1: C[((r&63)*SEQ + (r>>6))*N + c]  (b,s,v) layout.
__global__ __launch_bounds__(256) void gemm_bf16_nt(
    const unsigned short* __restrict__ A,
    const unsigned short* __restrict__ B,
    const float* __restrict__ bias,
    float* __restrict__ C,
    int M, int N, int K, int permute, int sb) {
    __shared__ unsigned short As[128 * 32];
    __shared__ unsigned short Bs[128 * 32];

    const int tid = threadIdx.x;
    const int wave = tid >> 6;
    const int lane = tid & 63;

    // XCD-aware supertile swizzle (requires gridDim.y % 8 == 0, gridDim.x % sb == 0)
    const int NX = gridDim.x;
    const int wg = blockIdx.y * NX + blockIdx.x;
    const int x = wg & 7;
    const int t = wg >> 3;
    const int grp = sb << 2;                 // 4 rows per chunk
    const int su = t / grp;
    const int r = t - su * grp;
    const int bn = su * sb + (r % sb);
    const int bm = x * (gridDim.y >> 3) + r / sb;

    const int wm = (wave >> 1) * 64;
    const int wn = (wave & 1) * 64;

    f32x4 acc[4][4];
#pragma unroll
    for (int i = 0; i < 4; i++)
#pragma unroll
        for (int j = 0; j < 4; j++) acc[i][j] = (f32x4){0.f, 0.f, 0.f, 0.f};

    // staging: thread t loads 8 bf16 (16B); chunk q covers 64 rows
    const int r0 = tid >> 2;              // 0..63
    const int c0 = (tid & 3) << 3;        // 0,8,16,24
    const unsigned short* Ap0 = A + (long)(bm * 128 + r0) * K + c0;
    const unsigned short* Ap1 = A + (long)(bm * 128 + 64 + r0) * K + c0;
    const unsigned short* Bp0 = B + (long)(bn * 128 + r0) * K + c0;
    const unsigned short* Bp1 = B + (long)(bn * 128 + 64 + r0) * K + c0;
    // wave-uniform LDS dest bases (elements): (q*256 + wave*64)*8
    unsigned short* AsW0 = &As[wave * 512];
    unsigned short* AsW1 = &As[2048 + wave * 512];
    unsigned short* BsW0 = &Bs[wave * 512];
    unsigned short* BsW1 = &Bs[2048 + wave * 512];

    const int fr = lane & 15;
    const int fk = (lane >> 4) << 3;

    for (int k0 = 0; k0 < K; k0 += 32) {
        __syncthreads();
        gld_lds16(Ap0 + k0, AsW0);
        gld_lds16(Ap1 + k0, AsW1);
        gld_lds16(Bp0 + k0, BsW0);
        gld_lds16(Bp1 + k0, BsW1);
        __syncthreads();  // drains vmcnt before barrier

        bf16_8 af[4], bf[4];
#pragma unroll
        for (int mt = 0; mt < 4; mt++)
            af[mt] = *(const bf16_8*)&As[(wm + mt * 16 + fr) * 32 + fk];
#pragma unroll
        for (int nt = 0; nt < 4; nt++)
            bf[nt] = *(const bf16_8*)&Bs[(wn + nt * 16 + fr) * 32 + fk];
#pragma unroll
        for (int mt = 0; mt < 4; mt++)
#pragma unroll
            for (int nt = 0; nt < 4; nt++)
                acc[mt][nt] = __builtin_amdgcn_mfma_f32_16x16x32_bf16(
                    af[mt], bf[nt], acc[mt][nt], 0, 0, 0);
    }

    // epilogue: C layout col=lane&15, row=(lane>>4)*4+i
    const int er = lane >> 4;
    const int ec = lane & 15;
#pragma unroll
    for (int nt = 0; nt < 4; nt++) {
        const int gc = bn * 128 + wn + nt * 16 + ec;
        const float bv = bias[gc];
#pragma unroll
        for (int mt = 0; mt < 4; mt++) {
#pragma unroll
            for (int i = 0; i < 4; i++) {
                int gr = bm * 128 + wm + mt * 16 + er * 4 + i;
                long off;
                if (permute) off = (long)((gr & 63) * SEQ + (gr >> 6)) * N + gc;
                else off = (long)gr * N + gc;
                C[off] = acc[mt][nt][i] + bv;
            }
        }
    }
}

// ---------------- fused persistent GRU: 64 steps, one plain-launch kernel ----------------
// Grid 256 blocks x 64 threads (1 wave). Block (mt=bid&3, jt) owns h-patch rows
// mt*16..+16 x cols jt*16..+16 for the whole sequence:
//  - r,z gate slices + low-half n slice (80 KB) staged into LDS ONCE, XOR-swizzled
//    (pre-swizzled global source, linear dest; read XOR'd back) to kill the
//    stride-2KB 16-way bank conflict on ds_read_b128. High-half n B-fragments
//    (64 VGPRs) loaded once from global. 80 KB -> 2 blocks/CU residency margin.
//  - f32 hidden patch lives in registers across all 64 steps (MFMA C layout).
//  - per step: prefetch gi -> grid barrier (slot stores + flag broadcast, device
//    scope, bounded spins) -> gh MFMA over K=1024 -> fused gates -> store bf16 h.
__global__ __launch_bounds__(64) void gru_fused_kernel(
    const unsigned short* __restrict__ w_hh,   // (3072,1024) bf16
    const float* __restrict__ gi,              // (4096,3072) f32 (includes b_ih)
    const float* __restrict__ b_hh,            // (3072)
    const float* __restrict__ h0,              // (64,1024) f32
    unsigned short* __restrict__ hb,           // (65,64,1024) bf16; hb[0] pre-filled
    unsigned* __restrict__ bar) {              // [256*16 slots][flag]
    __shared__ unsigned short Ws[(2 * 16 + 8) * 1024];  // 80 KB

    const int lane = threadIdx.x;
    const int bid = blockIdx.x;
    const int mt = bid & 3;                       // batch tile
    const int jt = (bid >> 3) | ((bid & 4) << 3); // j tile 0..63, XCD-spread
    const int fr = lane & 15;
    const int fk = (lane >> 4) << 3;
    const int er = lane >> 4;
    const int ec = lane & 15;

    unsigned* slots = bar;
    unsigned* flag = bar + 4096;

    // ---- stage r,z slices (full K) into LDS: swizzled source, linear dest ----
#pragma unroll
    for (int g = 0; g < 2; ++g) {
        const unsigned short* srcg = w_hh + (long)(g * HID + jt * 16) * HID;
#pragma unroll
        for (int i = 0; i < 32; ++i) {
            const int rr = i >> 1;                // row 0..15
            const int colel = (((i & 1) << 9) | (lane << 3)) ^ ((rr & 7) << 3);
            gld_lds16(srcg + rr * HID + colel, &Ws[g * 16384 + i * 512]);
        }
    }
    // ---- n slice, k<512 half into LDS (row stride 512 elems) ----
    {
        const unsigned short* srcn = w_hh + (long)(2 * HID + jt * 16) * HID;
#pragma unroll
        for (int i = 0; i < 16; ++i) {
            const int colel = (lane << 3) ^ ((i & 7) << 3);
            gld_lds16(srcn + i * HID + colel, &Ws[32768 + i * 512]);
        }
    }
    // ---- n slice, k>=512 half as B-fragments in VGPRs ----
    bf16_8 wnf[16];
    {
        const unsigned short* wn_g =
            w_hh + (long)(2 * HID + jt * 16 + fr) * HID + 512 + fk;
#pragma unroll
        for (int kk = 0; kk < 16; ++kk)
            wnf[kk] = *(const bf16_8*)(wn_g + (kk << 5));
    }

    const int j = jt * 16 + ec;
    const float bhr = b_hh[j];
    const float bhz = b_hh[HID + j];
    const float bhn = b_hh[2 * HID + j];

    // register-resident f32 h patch (MFMA C layout: row er*4+i, col ec)
    float hold[4];
#pragma unroll
    for (int i = 0; i < 4; ++i)
        hold[i] = h0[(mt * 16 + er * 4 + i) * HID + j];

    const int sw = (fr & 7) << 3;  // element-index XOR for swizzled LDS reads
    const unsigned short* Wr = &Ws[fr * HID];
    const unsigned short* Wz = &Ws[16384 + fr * HID];
    const unsigned short* Wn = &Ws[32768 + fr * 512];

    __syncthreads();  // drain global_load_lds

    for (int s = 0; s < SEQ; ++s) {
        // prefetch this step's gi slice — independent of the barrier
        float gir[4], giz[4], gin[4];
        {
            const float* gb = gi + (long)(s * BATCH + mt * 16 + er * 4) * (3 * HID) + j;
#pragma unroll
            for (int i = 0; i < 4; ++i) {
                gir[i] = gb[(long)i * 3 * HID];
                giz[i] = gb[(long)i * 3 * HID + HID];
                gin[i] = gb[(long)i * 3 * HID + 2 * HID];
            }
        }

        // ---- grid barrier #s: all hb[s] stores visible after this ----
        const unsigned ep = (unsigned)(s + 1);
        __threadfence();                       // release: own hb stores -> coherent
        if (lane == 0)
            __hip_atomic_store(slots + (bid << 4), ep,
                               __ATOMIC_RELAXED, __HIP_MEMORY_SCOPE_AGENT);
        if (bid == 0) {
            const int s0 = lane << 2;          // 4 slots per lane
            int spins = 0;
            for (;;) {
                unsigned a0 = __hip_atomic_load(slots + ((s0 + 0) << 4),
                                                __ATOMIC_RELAXED, __HIP_MEMORY_SCOPE_AGENT);
                unsigned a1 = __hip_atomic_load(slots + ((s0 + 1) << 4),
                                                __ATOMIC_RELAXED, __HIP_MEMORY_SCOPE_AGENT);
                unsigned a2 = __hip_atomic_load(slots + ((s0 + 2) << 4),
                                                __ATOMIC_RELAXED, __HIP_MEMORY_SCOPE_AGENT);
                unsigned a3 = __hip_atomic_load(slots + ((s0 + 3) << 4),
                                                __ATOMIC_RELAXED, __HIP_MEMORY_SCOPE_AGENT);
                if (a0 >= ep && a1 >= ep && a2 >= ep && a3 >= ep) break;
                if (++spins > 20000) break;    // safety valve: no container hang
                __builtin_amdgcn_s_sleep(1);
            }
            __threadfence();
            if (lane == 0)
                __hip_atomic_store(flag, ep,
                                   __ATOMIC_RELAXED, __HIP_MEMORY_SCOPE_AGENT);
        } else {
            int spins = 0;
            while (__hip_atomic_load(flag, __ATOMIC_RELAXED,
                                     __HIP_MEMORY_SCOPE_AGENT) < ep) {
                if (++spins > 20000) break;    // safety valve
                __builtin_amdgcn_s_sleep(4);
            }
        }
        __threadfence();                       // acquire: invalidate L1 before reads

        const unsigned short* aptr =
            hb + (long)s * BATCH * HID + (mt * 16 + fr) * HID + fk;
        f32x4 accr = (f32x4){0.f, 0.f, 0.f, 0.f};
        f32x4 accz = (f32x4){0.f, 0.f, 0.f, 0.f};
        f32x4 accn = (f32x4){0.f, 0.f, 0.f, 0.f};
#pragma unroll
        for (int kk = 0; kk < 32; ++kk) {
            const int k = kk << 5;
            const int kc = (k + fk) ^ sw;
            bf16_8 a = *(const bf16_8*)(aptr + k);
            bf16_8 br = *(const bf16_8*)(Wr + kc);
            bf16_8 bz = *(const bf16_8*)(Wz + kc);
            accr = __builtin_amdgcn_mfma_f32_16x16x32_bf16(a, br, accr, 0, 0, 0);
            accz = __builtin_amdgcn_mfma_f32_16x16x32_bf16(a, bz, accz, 0, 0, 0);
            bf16_8 bn = (kk < 16) ? *(const bf16_8*)(Wn + kc) : wnf[kk - 16];
            accn = __builtin_amdgcn_mfma_f32_16x16x32_bf16(a, bn, accn, 0, 0, 0);
        }

        unsigned short* hb_out = hb + (long)(s + 1) * BATCH * HID;
#pragma unroll
        for (int i = 0; i < 4; ++i) {
            const int b = mt * 16 + er * 4 + i;
            float ghr = accr[i] + bhr;
            float ghz = accz[i] + bhz;
            float ghn = accn[i] + bhn;
            float rg = 1.f / (1.f + __expf(-(gir[i] + ghr)));
            float zg = 1.f / (1.f + __expf(-(giz[i] + ghz)));
            float ng = tanhf(gin[i] + rg * ghn);
            float hn = (1.f - zg) * ng + zg * hold[i];
            hold[i] = hn;
            hb_out[b * HID + j] = f32_to_bf16_rne(hn);
        }
    }
}

extern "C" void kernel_launch(void* const* d_in, const int* in_sizes, int n_in,
                              void* d_out, int out_size, void* d_ws, size_t ws_size,
                              hipStream_t stream) {
    const int* x = (const int*)d_in[0];
    const float* hidden = (const float*)d_in[1];
    const float* emb = (const float*)d_in[2];
    const float* w_ih = (const float*)d_in[3];
    const float* w_hh = (const float*)d_in[4];
    const float* b_ih = (const float*)d_in[5];
    const float* b_hh = (const float*)d_in[6];
    const float* w_out = (const float*)d_in[7];
    const float* b_out = (const float*)d_in[8];
    float* out = (float*)d_out;

    char* ws = (char*)d_ws;
    // workspace layout (all offsets 256B aligned)
    unsigned short* w_ih_bf  = (unsigned short*)(ws + 0);            //  3,145,728 B
    unsigned short* w_hh_bf  = (unsigned short*)(ws + 3145728);      //  6,291,456 B
    unsigned short* w_out_bf = (unsigned short*)(ws + 9437184);      // 65,536,000 B
    unsigned short* e_bf     = (unsigned short*)(ws + 74973184);     //  4,194,304 B
    float*          gi       = (float*)(ws + 79167488);              // 50,331,648 B
    unsigned*       bar      = (unsigned*)(ws + 129499136);          //     18,432 B
    unsigned short* hb       = (unsigned short*)(ws + 146538496);    //  8,519,680 B

    // 1. convert weights to bf16
    f32_to_bf16_vec<<<(3 * HID * EMB / 4 + 255) / 256, 256, 0, stream>>>(w_ih, w_ih_bf, 3 * HID * EMB / 4);
    f32_to_bf16_vec<<<(3 * HID * HID / 4 + 255) / 256, 256, 0, stream>>>(w_hh, w_hh_bf, 3 * HID * HID / 4);
    f32_to_bf16_vec<<<(VOCAB * HID / 4 + 255) / 256, 256, 0, stream>>>(w_out, w_out_bf, VOCAB * HID / 4);

    // 2. h0 -> hb[0]; zero barrier region
    init_h_kernel<<<BATCH * HID / 256, 256, 0, stream>>>(hidden, hb, bar);

    // 3. embedding gather + relu -> e_bf (4096, 512)
    embed_relu_kernel<<<SEQ * BATCH * EMB / 256, 256, 0, stream>>>(x, emb, e_bf);

    // 4. gi = e @ w_ih^T + b_ih : (4096, 3072), K=512
    {
        dim3 grid(3 * HID / 128, SEQ * BATCH / 128);
        gemm_bf16_nt<<<grid, 256, 0, stream>>>(e_bf, w_ih_bf, b_ih, gi,
                                               SEQ * BATCH, 3 * HID, EMB, 0, 8);
    }

    // 5. all 64 GRU steps in ONE plain-launch persistent kernel
    gru_fused_kernel<<<256, 64, 0, stream>>>(w_hh_bf, gi, b_hh, hidden, hb, bar);

    // 6. logits = hs @ w_out^T + b_out, stored as (B, S, V)
    {
        dim3 grid(VOCAB / 128, SEQ * BATCH / 128);
        gemm_bf16_nt<<<grid, 256, 0, stream>>>(hb + BATCH * HID, w_out_bf, b_out, out,
                                               SEQ * BATCH, VOCAB, HID, 1, 10);
    }
}

// Round 3
// 1276.215 us; speedup vs baseline: 1.6417x; 1.6417x over previous
//
#include <hip/hip_runtime.h>
#include <hip/hip_bf16.h>

// DecoderRNN: emb gather+relu -> gi GEMM (hoisted) -> ONE persistent GRU kernel
// (64 steps; 4 waves/block with K split 4x256 + LDS reduce; w_hh LDS/VGPR-resident;
// h-state f32 in wave0 registers; per-mt-group all-to-all grid barrier built from
// agent-scope relaxed atomics + s_waitcnt vmcnt(0) -- NO threadfence/L2-writeback)
// -> output projection GEMM (4096x32000x1024 bf16 MFMA) with permuted (b,s,v)
// store + bias. GEMMs are the round-0 verified code (swizzle reverted).
//
// Sizes: VOCAB=32000, EMB=512, HID=1024, SEQ=64, BATCH=64.

#define VOCAB 32000
#define EMB 512
#define HID 1024
#define SEQ 64
#define BATCH 64

typedef __bf16 bf16_8 __attribute__((ext_vector_type(8)));
typedef float f32x4 __attribute__((ext_vector_type(4)));

__device__ __forceinline__ unsigned short f32_to_bf16_rne(float f) {
    unsigned int u = __float_as_uint(f);
    u = (u + 0x7FFFu + ((u >> 16) & 1u)) >> 16;
    return (unsigned short)u;
}

__device__ __forceinline__ void gld_lds16(const unsigned short* g, unsigned short* l) {
    __builtin_amdgcn_global_load_lds(
        (__attribute__((address_space(1))) void*)g,
        (__attribute__((address_space(3))) void*)l, 16, 0, 0);
}

// ---------------- converters ----------------
__global__ void f32_to_bf16_vec(const float* __restrict__ in,
                                unsigned short* __restrict__ out, int n4) {
    int i = blockIdx.x * blockDim.x + threadIdx.x;
    if (i < n4) {
        float4 v = ((const float4*)in)[i];
        ushort4 o;
        o.x = f32_to_bf16_rne(v.x);
        o.y = f32_to_bf16_rne(v.y);
        o.z = f32_to_bf16_rne(v.z);
        o.w = f32_to_bf16_rne(v.w);
        ((ushort4*)out)[i] = o;
    }
}

// h0 -> bf16, and zero the grid-barrier region (fresh per graph replay)
__global__ void init_h_kernel(const float* __restrict__ h0,
                              unsigned short* __restrict__ hb0,
                              unsigned* __restrict__ bar) {
    int i = blockIdx.x * blockDim.x + threadIdx.x;  // 65536
    if (i < 4608) bar[i] = 0;                       // 4*64 slots * 16 u32
    hb0[i] = f32_to_bf16_rne(h0[i]);
}

// ---------------- embedding gather + relu -> bf16 ----------------
__global__ void embed_relu_kernel(const int* __restrict__ x,
                                  const float* __restrict__ emb,
                                  unsigned short* __restrict__ e_bf) {
    int idx = blockIdx.x * blockDim.x + threadIdx.x;  // 4096*512
    int row = idx >> 9;       // (s*64+b)
    int k = idx & 511;
    int s = row >> 6, b = row & 63;
    int tok = (s == 0) ? 2 : x[(s - 1) * 64 + b];
    float v = emb[(long)tok * EMB + k];
    v = v > 0.f ? v : 0.f;   // relu (also covers padding row 0, already zero)
    e_bf[idx] = f32_to_bf16_rne(v);
}

// ---------------- bf16 MFMA GEMM: C(M,N) = A(M,K) * B(N,K)^T + bias ----------------
// Round-0 verified version (435 us on the 32000-col GEMM). No block swizzle.
// permute=0: C[r*N+c]; permute=1: C[((r&63)*SEQ + (r>>6))*N + c]  (b,s,v) layout.
__global__ __launch_bounds__(256) void gemm_bf16_nt(
    const unsigned short* __restrict__ A,
    const unsigned short* __restrict__ B,
    const float* __restrict__ bias,
    float* __restrict__ C,
    int M, int N, int K, int permute) {
    __shared__ unsigned short As[128 * 32];
    __shared__ unsigned short Bs[128 * 32];

    const int tid = threadIdx.x;
    const int wave = tid >> 6;
    const int lane = tid & 63;
    const int bm = blockIdx.y, bn = blockIdx.x;
    const int wm = (wave >> 1) * 64;
    const int wn = (wave & 1) * 64;

    f32x4 acc[4][4];
#pragma unroll
    for (int i = 0; i < 4; i++)
#pragma unroll
        for (int j = 0; j < 4; j++) acc[i][j] = (f32x4){0.f, 0.f, 0.f, 0.f};

    // staging: thread t loads 8 bf16 (16B); chunk q covers 64 rows
    const int r0 = tid >> 2;              // 0..63
    const int c0 = (tid & 3) << 3;        // 0,8,16,24
    const unsigned short* Ap0 = A + (long)(bm * 128 + r0) * K + c0;
    const unsigned short* Ap1 = A + (long)(bm * 128 + 64 + r0) * K + c0;
    const unsigned short* Bp0 = B + (long)(bn * 128 + r0) * K + c0;
    const unsigned short* Bp1 = B + (long)(bn * 128 + 64 + r0) * K + c0;
    // wave-uniform LDS dest bases (elements): (q*256 + wave*64)*8
    unsigned short* AsW0 = &As[wave * 512];
    unsigned short* AsW1 = &As[2048 + wave * 512];
    unsigned short* BsW0 = &Bs[wave * 512];
    unsigned short* BsW1 = &Bs[2048 + wave * 512];

    const int fr = lane & 15;
    const int fk = (lane >> 4) << 3;

    for (int k0 = 0; k0 < K; k0 += 32) {
        __syncthreads();
        gld_lds16(Ap0 + k0, AsW0);
        gld_lds16(Ap1 + k0, AsW1);
        gld_lds16(Bp0 + k0, BsW0);
        gld_lds16(Bp1 + k0, BsW1);
        __syncthreads();  // drains vmcnt before barrier

        bf16_8 af[4], bf[4];
#pragma unroll
        for (int mt = 0; mt < 4; mt++)
            af[mt] = *(const bf16_8*)&As[(wm + mt * 16 + fr) * 32 + fk];
#pragma unroll
        for (int nt = 0; nt < 4; nt++)
            bf[nt] = *(const bf16_8*)&Bs[(wn + nt * 16 + fr) * 32 + fk];
#pragma unroll
        for (int mt = 0; mt < 4; mt++)
#pragma unroll
            for (int nt = 0; nt < 4; nt++)
                acc[mt][nt] = __builtin_amdgcn_mfma_f32_16x16x32_bf16(
                    af[mt], bf[nt], acc[mt][nt], 0, 0, 0);
    }

    // epilogue: C layout col=lane&15, row=(lane>>4)*4+i
    const int er = lane >> 4;
    const int ec = lane & 15;
#pragma unroll
    for (int nt = 0; nt < 4; nt++) {
        const int gc = bn * 128 + wn + nt * 16 + ec;
        const float bv = bias[gc];
#pragma unroll
        for (int mt = 0; mt < 4; mt++) {
#pragma unroll
            for (int i = 0; i < 4; i++) {
                int gr = bm * 128 + wm + mt * 16 + er * 4 + i;
                long off;
                if (permute) off = (long)((gr & 63) * SEQ + (gr >> 6)) * N + gc;
                else off = (long)gr * N + gc;
                C[off] = acc[mt][nt][i] + bv;
            }
        }
    }
}

// ---------------- fused persistent GRU v3 ----------------
// Grid 256 blocks x 256 threads (4 waves). Block (mt=bid&3, jt) owns the h-patch
// rows mt*16..+16 x cols jt*16..+16 for the whole sequence.
//  - r,z gate slices (64 KB) staged into LDS once, XOR-swizzled (pre-swizzled
//    global source, linear dest; reads XOR back). n-gate: each wave keeps its
//    K-quarter as B-fragments in 32 VGPRs.
//  - K=1024 split 4x256 across waves; partials reduced via 9 KB LDS; wave 0 does
//    gate math; f32 h-patch lives in wave 0's registers (MFMA C layout).
//  - h stores are agent-scope relaxed atomics (sc1 write-through to LLC); barrier
//    = s_waitcnt vmcnt(0) + slot store + all-to-all poll of the 64-block mt-group
//    (agent-scope loads force L2 miss -> coherent). NO threadfence, no L2 wb/inv.
//  - plain hb loads are safe: every hb region is first-touch within a launch;
//    dispatch-boundary CP acquire covers graph replays.
__global__ __launch_bounds__(256) void gru_fused_kernel(
    const unsigned short* __restrict__ w_hh,   // (3072,1024) bf16
    const float* __restrict__ gi,              // (4096,3072) f32 (includes b_ih)
    const float* __restrict__ b_hh,            // (3072)
    const float* __restrict__ h0,              // (64,1024) f32
    unsigned short* __restrict__ hb,           // (65,64,1024) bf16; hb[0] pre-filled
    unsigned* __restrict__ bar) {              // 4 groups x 64 slots x 16 u32
    __shared__ unsigned short Ws[2 * 16 * 1024];  // 64 KB: r,z gate slices
    __shared__ float Ps[9 * 64 * 4];              // 9 KB: partials of waves 1..3

    const int tid = threadIdx.x;
    const int wave = tid >> 6;
    const int lane = tid & 63;
    const int bid = blockIdx.x;
    const int mt = bid & 3;                        // batch tile
    const int jt = (bid >> 3) | ((bid & 4) << 3);  // j tile 0..63, XCD-spread
    const int fr = lane & 15;
    const int fk = (lane >> 4) << 3;
    const int er = lane >> 4;
    const int ec = lane & 15;
    const int kbase = wave << 8;                   // this wave's K-quarter

    unsigned* grp_slots = bar + (mt << 10);        // 64 slots * 16 u32

    // ---- stage r,z slices into LDS: swizzled source, linear dest (16 loads/wave) ----
#pragma unroll
    for (int ii = 0; ii < 16; ++ii) {
        const int i = wave * 16 + ii;              // 0..63
        const int g = i >> 5;                      // gate 0,1
        const int rr = (i >> 1) & 15;              // row 0..15
        const int half = i & 1;                    // k-half
        const unsigned short* src = w_hh + (long)(g * HID + jt * 16 + rr) * HID;
        const int colel = ((half << 9) | (lane << 3)) ^ ((rr & 7) << 3);
        gld_lds16(src + colel, &Ws[g * 16384 + (rr * 2 + half) * 512]);
    }

    // ---- n-gate K-quarter as B-fragments in VGPRs ----
    bf16_8 wnf[8];
    {
        const unsigned short* wn_g =
            w_hh + (long)(2 * HID + jt * 16 + fr) * HID + kbase + fk;
#pragma unroll
        for (int kk = 0; kk < 8; ++kk)
            wnf[kk] = *(const bf16_8*)(wn_g + (kk << 5));
    }

    const int j = jt * 16 + ec;
    float bhr = 0.f, bhz = 0.f, bhn = 0.f;
    float hold[4] = {0.f, 0.f, 0.f, 0.f};
    float gir[4], giz[4], gin[4];
    if (wave == 0) {
        bhr = b_hh[j];
        bhz = b_hh[HID + j];
        bhn = b_hh[2 * HID + j];
#pragma unroll
        for (int i = 0; i < 4; ++i)
            hold[i] = h0[(mt * 16 + er * 4 + i) * HID + j];
        // gi for step 0
        const float* gb = gi + (long)(mt * 16 + er * 4) * (3 * HID) + j;
#pragma unroll
        for (int i = 0; i < 4; ++i) {
            gir[i] = gb[(long)i * 3 * HID];
            giz[i] = gb[(long)i * 3 * HID + HID];
            gin[i] = gb[(long)i * 3 * HID + 2 * HID];
        }
    }

    const int sw = (fr & 7) << 3;  // element-index XOR for swizzled LDS reads

    __syncthreads();  // drain global_load_lds staging

    for (int s = 0; s < SEQ; ++s) {
        // ---- K-quarter MFMA: gh partials for this wave ----
        const unsigned short* aptr =
            hb + (long)s * BATCH * HID + (mt * 16 + fr) * HID + kbase + fk;
        f32x4 accr = (f32x4){0.f, 0.f, 0.f, 0.f};
        f32x4 accz = (f32x4){0.f, 0.f, 0.f, 0.f};
        f32x4 accn = (f32x4){0.f, 0.f, 0.f, 0.f};
#pragma unroll
        for (int kk = 0; kk < 8; ++kk) {
            const int kc = (kbase + (kk << 5) + fk) ^ sw;
            bf16_8 a = *(const bf16_8*)(aptr + (kk << 5));
            bf16_8 br = *(const bf16_8*)&Ws[fr * 1024 + kc];
            bf16_8 bz = *(const bf16_8*)&Ws[16384 + fr * 1024 + kc];
            accr = __builtin_amdgcn_mfma_f32_16x16x32_bf16(a, br, accr, 0, 0, 0);
            accz = __builtin_amdgcn_mfma_f32_16x16x32_bf16(a, bz, accz, 0, 0, 0);
            accn = __builtin_amdgcn_mfma_f32_16x16x32_bf16(a, wnf[kk], accn, 0, 0, 0);
        }

        if (wave != 0) {
            float* p = &Ps[(((wave - 1) * 3) * 64 + lane) * 4];
            *(f32x4*)(p) = accr;
            *(f32x4*)(p + 256) = accz;   // (+1 gate)*64 lanes*4
            *(f32x4*)(p + 512) = accn;
        }
        __syncthreads();  // partials visible to wave 0

        if (wave == 0) {
            // reduce 3 other waves' partials
#pragma unroll
            for (int w2 = 0; w2 < 3; ++w2) {
                const float* p = &Ps[((w2 * 3) * 64 + lane) * 4];
                accr += *(const f32x4*)(p);
                accz += *(const f32x4*)(p + 256);
                accn += *(const f32x4*)(p + 512);
            }

            unsigned short* hb_out = hb + (long)(s + 1) * BATCH * HID;
#pragma unroll
            for (int i = 0; i < 4; ++i) {
                const int b = mt * 16 + er * 4 + i;
                float ghr = accr[i] + bhr;
                float ghz = accz[i] + bhz;
                float ghn = accn[i] + bhn;
                float rg = 1.f / (1.f + __expf(-(gir[i] + ghr)));
                float zg = 1.f / (1.f + __expf(-(giz[i] + ghz)));
                float ng = tanhf(gin[i] + rg * ghn);
                float hn = (1.f - zg) * ng + zg * hold[i];
                hold[i] = hn;
                __hip_atomic_store(&hb_out[b * HID + j], f32_to_bf16_rne(hn),
                                   __ATOMIC_RELAXED, __HIP_MEMORY_SCOPE_AGENT);
            }

            if (s < SEQ - 1) {
                const unsigned ep = (unsigned)(s + 1);
                // release: h stores acknowledged at coherence point before arrive
                asm volatile("s_waitcnt vmcnt(0)" ::: "memory");
                if (lane == 0)
                    __hip_atomic_store(grp_slots + (jt << 4), ep,
                                       __ATOMIC_RELAXED, __HIP_MEMORY_SCOPE_AGENT);
                // prefetch next step's gi while polling
                {
                    const float* gb =
                        gi + (long)((s + 1) * BATCH + mt * 16 + er * 4) * (3 * HID) + j;
#pragma unroll
                    for (int i = 0; i < 4; ++i) {
                        gir[i] = gb[(long)i * 3 * HID];
                        giz[i] = gb[(long)i * 3 * HID + HID];
                        gin[i] = gb[(long)i * 3 * HID + 2 * HID];
                    }
                }
                // all-to-all poll: lane L watches slot of block (mt, jt=L)
                int spins = 0;
                for (;;) {
                    unsigned v = __hip_atomic_load(grp_slots + (lane << 4),
                                                   __ATOMIC_RELAXED,
                                                   __HIP_MEMORY_SCOPE_AGENT);
                    if (__all(v >= ep)) break;
                    if (++spins > 30000) break;  // safety valve: no container hang
                    __builtin_amdgcn_s_sleep(2);
                }
            }
        }
        __syncthreads();  // release waves 1..3 into the next step
    }
}

extern "C" void kernel_launch(void* const* d_in, const int* in_sizes, int n_in,
                              void* d_out, int out_size, void* d_ws, size_t ws_size,
                              hipStream_t stream) {
    const int* x = (const int*)d_in[0];
    const float* hidden = (const float*)d_in[1];
    const float* emb = (const float*)d_in[2];
    const float* w_ih = (const float*)d_in[3];
    const float* w_hh = (const float*)d_in[4];
    const float* b_ih = (const float*)d_in[5];
    const float* b_hh = (const float*)d_in[6];
    const float* w_out = (const float*)d_in[7];
    const float* b_out = (const float*)d_in[8];
    float* out = (float*)d_out;

    char* ws = (char*)d_ws;
    // workspace layout (all offsets 256B aligned)
    unsigned short* w_ih_bf  = (unsigned short*)(ws + 0);            //  3,145,728 B
    unsigned short* w_hh_bf  = (unsigned short*)(ws + 3145728);      //  6,291,456 B
    unsigned short* w_out_bf = (unsigned short*)(ws + 9437184);      // 65,536,000 B
    unsigned short* e_bf     = (unsigned short*)(ws + 74973184);     //  4,194,304 B
    float*          gi       = (float*)(ws + 79167488);              // 50,331,648 B
    unsigned*       bar      = (unsigned*)(ws + 129499136);          //     18,432 B
    unsigned short* hb       = (unsigned short*)(ws + 146538496);    //  8,519,680 B

    // 1. convert weights to bf16
    f32_to_bf16_vec<<<(3 * HID * EMB / 4 + 255) / 256, 256, 0, stream>>>(w_ih, w_ih_bf, 3 * HID * EMB / 4);
    f32_to_bf16_vec<<<(3 * HID * HID / 4 + 255) / 256, 256, 0, stream>>>(w_hh, w_hh_bf, 3 * HID * HID / 4);
    f32_to_bf16_vec<<<(VOCAB * HID / 4 + 255) / 256, 256, 0, stream>>>(w_out, w_out_bf, VOCAB * HID / 4);

    // 2. h0 -> hb[0]; zero barrier region
    init_h_kernel<<<BATCH * HID / 256, 256, 0, stream>>>(hidden, hb, bar);

    // 3. embedding gather + relu -> e_bf (4096, 512)
    embed_relu_kernel<<<SEQ * BATCH * EMB / 256, 256, 0, stream>>>(x, emb, e_bf);

    // 4. gi = e @ w_ih^T + b_ih : (4096, 3072), K=512
    {
        dim3 grid(3 * HID / 128, SEQ * BATCH / 128);
        gemm_bf16_nt<<<grid, 256, 0, stream>>>(e_bf, w_ih_bf, b_ih, gi,
                                               SEQ * BATCH, 3 * HID, EMB, 0);
    }

    // 5. all 64 GRU steps in ONE plain-launch persistent kernel
    gru_fused_kernel<<<256, 256, 0, stream>>>(w_hh_bf, gi, b_hh, hidden, hb, bar);

    // 6. logits = hs @ w_out^T + b_out, stored as (B, S, V)
    {
        dim3 grid(VOCAB / 128, SEQ * BATCH / 128);
        gemm_bf16_nt<<<grid, 256, 0, stream>>>(hb + BATCH * HID, w_out_bf, b_out, out,
                                               SEQ * BATCH, VOCAB, HID, 1);
    }
}

// Round 5
// 1255.915 us; speedup vs baseline: 1.6682x; 1.0162x over previous
//
#include <hip/hip_runtime.h>
#include <hip/hip_bf16.h>

// DecoderRNN: emb gather+relu -> gi GEMM (hoisted) -> ONE persistent GRU kernel
// (64 steps; 4 waves/block with K split 4x256 + LDS reduce; w_hh LDS/VGPR-resident;
// h-state f32 in wave0 registers; per-mt-group grid barrier from agent-scope
// relaxed atomics + s_waitcnt vmcnt(0)) -> output projection GEMM
// (4096x32000x1024 bf16 MFMA, XCD-swizzled, NONTEMPORAL C stores so the 524MB
// C stream doesn't evict the 65.5MB B from L3) with permuted (b,s,v) store + bias.
//
// GRU kernel is byte-identical to the round-2 submission verified at 1276us
// (one-delta discipline after an unexplained container failure).
//
// Sizes: VOCAB=32000, EMB=512, HID=1024, SEQ=64, BATCH=64.

#define VOCAB 32000
#define EMB 512
#define HID 1024
#define SEQ 64
#define BATCH 64

typedef __bf16 bf16_8 __attribute__((ext_vector_type(8)));
typedef float f32x4 __attribute__((ext_vector_type(4)));

__device__ __forceinline__ unsigned short f32_to_bf16_rne(float f) {
    unsigned int u = __float_as_uint(f);
    u = (u + 0x7FFFu + ((u >> 16) & 1u)) >> 16;
    return (unsigned short)u;
}

__device__ __forceinline__ void gld_lds16(const unsigned short* g, unsigned short* l) {
    __builtin_amdgcn_global_load_lds(
        (__attribute__((address_space(1))) void*)g,
        (__attribute__((address_space(3))) void*)l, 16, 0, 0);
}

// ---------------- converters ----------------
__global__ void f32_to_bf16_vec(const float* __restrict__ in,
                                unsigned short* __restrict__ out, int n4) {
    int i = blockIdx.x * blockDim.x + threadIdx.x;
    if (i < n4) {
        float4 v = ((const float4*)in)[i];
        ushort4 o;
        o.x = f32_to_bf16_rne(v.x);
        o.y = f32_to_bf16_rne(v.y);
        o.z = f32_to_bf16_rne(v.z);
        o.w = f32_to_bf16_rne(v.w);
        ((ushort4*)out)[i] = o;
    }
}

// h0 -> bf16, and zero the grid-barrier region (fresh per graph replay)
__global__ void init_h_kernel(const float* __restrict__ h0,
                              unsigned short* __restrict__ hb0,
                              unsigned* __restrict__ bar) {
    int i = blockIdx.x * blockDim.x + threadIdx.x;  // 65536
    if (i < 4608) bar[i] = 0;                       // 4*64 slots * 16 u32
    hb0[i] = f32_to_bf16_rne(h0[i]);
}

// ---------------- embedding gather + relu -> bf16 ----------------
__global__ void embed_relu_kernel(const int* __restrict__ x,
                                  const float* __restrict__ emb,
                                  unsigned short* __restrict__ e_bf) {
    int idx = blockIdx.x * blockDim.x + threadIdx.x;  // 4096*512
    int row = idx >> 9;       // (s*64+b)
    int k = idx & 511;
    int s = row >> 6, b = row & 63;
    int tok = (s == 0) ? 2 : x[(s - 1) * 64 + b];
    float v = emb[(long)tok * EMB + k];
    v = v > 0.f ? v : 0.f;   // relu (also covers padding row 0, already zero)
    e_bf[idx] = f32_to_bf16_rne(v);
}

// ---------------- bf16 MFMA GEMM: C(M,N) = A(M,K) * B(N,K)^T + bias ----------------
// 128x128 block tile, BK=32, 4 waves (2x2), each wave 64x64 via 4x4 mfma_16x16x32.
// XCD swizzle (m192 form; nwg % 8 == 0 at both call sites): each XCD gets a
// contiguous swz chunk; within it consecutive blocks share bm (A panel L2-hot)
// and walk bn (B streamed once into L3, reused by later bm rows).
// permute=1 (output GEMM): nontemporal C stores -- round-3 counters showed
// FETCH=1.13GB = 17x B's 65.5MB because the 524MB C stream evicts B from L3.
// permute=0: C[r*N+c]; permute=1: C[((r&63)*SEQ + (r>>6))*N + c]  (b,s,v) layout.
__global__ __launch_bounds__(256) void gemm_bf16_nt(
    const unsigned short* __restrict__ A,
    const unsigned short* __restrict__ B,
    const float* __restrict__ bias,
    float* __restrict__ C,
    int M, int N, int K, int permute) {
    __shared__ unsigned short As[128 * 32];
    __shared__ unsigned short Bs[128 * 32];

    const int tid = threadIdx.x;
    const int wave = tid >> 6;
    const int lane = tid & 63;

    const int gx = gridDim.x;
    const int nwg = gx * gridDim.y;
    const int wg = blockIdx.y * gx + blockIdx.x;
    const int swz = (wg & 7) * (nwg >> 3) + (wg >> 3);
    const int bm = swz / gx;
    const int bn = swz % gx;

    const int wm = (wave >> 1) * 64;
    const int wn = (wave & 1) * 64;

    f32x4 acc[4][4];
#pragma unroll
    for (int i = 0; i < 4; i++)
#pragma unroll
        for (int j = 0; j < 4; j++) acc[i][j] = (f32x4){0.f, 0.f, 0.f, 0.f};

    // staging: thread t loads 8 bf16 (16B); chunk q covers 64 rows
    const int r0 = tid >> 2;              // 0..63
    const int c0 = (tid & 3) << 3;        // 0,8,16,24
    const unsigned short* Ap0 = A + (long)(bm * 128 + r0) * K + c0;
    const unsigned short* Ap1 = A + (long)(bm * 128 + 64 + r0) * K + c0;
    const unsigned short* Bp0 = B + (long)(bn * 128 + r0) * K + c0;
    const unsigned short* Bp1 = B + (long)(bn * 128 + 64 + r0) * K + c0;
    // wave-uniform LDS dest bases (elements): (q*256 + wave*64)*8
    unsigned short* AsW0 = &As[wave * 512];
    unsigned short* AsW1 = &As[2048 + wave * 512];
    unsigned short* BsW0 = &Bs[wave * 512];
    unsigned short* BsW1 = &Bs[2048 + wave * 512];

    const int fr = lane & 15;
    const int fk = (lane >> 4) << 3;

    for (int k0 = 0; k0 < K; k0 += 32) {
        __syncthreads();
        gld_lds16(Ap0 + k0, AsW0);
        gld_lds16(Ap1 + k0, AsW1);
        gld_lds16(Bp0 + k0, BsW0);
        gld_lds16(Bp1 + k0, BsW1);
        __syncthreads();  // drains vmcnt before barrier

        bf16_8 af[4], bf[4];
#pragma unroll
        for (int mt = 0; mt < 4; mt++)
            af[mt] = *(const bf16_8*)&As[(wm + mt * 16 + fr) * 32 + fk];
#pragma unroll
        for (int nt = 0; nt < 4; nt++)
            bf[nt] = *(const bf16_8*)&Bs[(wn + nt * 16 + fr) * 32 + fk];
#pragma unroll
        for (int mt = 0; mt < 4; mt++)
#pragma unroll
            for (int nt = 0; nt < 4; nt++)
                acc[mt][nt] = __builtin_amdgcn_mfma_f32_16x16x32_bf16(
                    af[mt], bf[nt], acc[mt][nt], 0, 0, 0);
    }

    // epilogue: C layout col=lane&15, row=(lane>>4)*4+i
    const int er = lane >> 4;
    const int ec = lane & 15;
#pragma unroll
    for (int nt = 0; nt < 4; nt++) {
        const int gc = bn * 128 + wn + nt * 16 + ec;
        const float bv = bias[gc];
#pragma unroll
        for (int mt = 0; mt < 4; mt++) {
#pragma unroll
            for (int i = 0; i < 4; i++) {
                int gr = bm * 128 + wm + mt * 16 + er * 4 + i;
                if (permute) {
                    long off = (long)((gr & 63) * SEQ + (gr >> 6)) * N + gc;
                    __builtin_nontemporal_store(acc[mt][nt][i] + bv, &C[off]);
                } else {
                    C[(long)gr * N + gc] = acc[mt][nt][i] + bv;
                }
            }
        }
    }
}

// ---------------- fused persistent GRU v3 (verified round-3, byte-identical) ----------------
// Grid 256 blocks x 256 threads (4 waves). Block (mt=bid&3, jt) owns the h-patch
// rows mt*16..+16 x cols jt*16..+16 for the whole sequence.
//  - r,z gate slices (64 KB) staged into LDS once, XOR-swizzled (pre-swizzled
//    global source, linear dest; reads XOR back). n-gate: each wave keeps its
//    K-quarter as B-fragments in 32 VGPRs.
//  - K=1024 split 4x256 across waves; partials reduced via 9 KB LDS; wave 0 does
//    gate math; f32 h-patch lives in wave 0's registers (MFMA C layout).
//  - h stores are agent-scope relaxed atomics (sc1 write-through to LLC); barrier
//    = s_waitcnt vmcnt(0) + slot store + all-to-all poll of the 64-block mt-group
//    (agent-scope loads force L2 miss -> coherent). NO threadfence, no L2 wb/inv.
//  - plain hb loads are safe: every hb region is first-touch within a launch;
//    dispatch-boundary CP acquire covers graph replays.
__global__ __launch_bounds__(256) void gru_fused_kernel(
    const unsigned short* __restrict__ w_hh,   // (3072,1024) bf16
    const float* __restrict__ gi,              // (4096,3072) f32 (includes b_ih)
    const float* __restrict__ b_hh,            // (3072)
    const float* __restrict__ h0,              // (64,1024) f32
    unsigned short* __restrict__ hb,           // (65,64,1024) bf16; hb[0] pre-filled
    unsigned* __restrict__ bar) {              // 4 groups x 64 slots x 16 u32
    __shared__ unsigned short Ws[2 * 16 * 1024];  // 64 KB: r,z gate slices
    __shared__ float Ps[9 * 64 * 4];              // 9 KB: partials of waves 1..3

    const int tid = threadIdx.x;
    const int wave = tid >> 6;
    const int lane = tid & 63;
    const int bid = blockIdx.x;
    const int mt = bid & 3;                        // batch tile
    const int jt = (bid >> 3) | ((bid & 4) << 3);  // j tile 0..63, XCD-spread
    const int fr = lane & 15;
    const int fk = (lane >> 4) << 3;
    const int er = lane >> 4;
    const int ec = lane & 15;
    const int kbase = wave << 8;                   // this wave's K-quarter

    unsigned* grp_slots = bar + (mt << 10);        // 64 slots * 16 u32

    // ---- stage r,z slices into LDS: swizzled source, linear dest (16 loads/wave) ----
#pragma unroll
    for (int ii = 0; ii < 16; ++ii) {
        const int i = wave * 16 + ii;              // 0..63
        const int g = i >> 5;                      // gate 0,1
        const int rr = (i >> 1) & 15;              // row 0..15
        const int half = i & 1;                    // k-half
        const unsigned short* src = w_hh + (long)(g * HID + jt * 16 + rr) * HID;
        const int colel = ((half << 9) | (lane << 3)) ^ ((rr & 7) << 3);
        gld_lds16(src + colel, &Ws[g * 16384 + (rr * 2 + half) * 512]);
    }

    // ---- n-gate K-quarter as B-fragments in VGPRs ----
    bf16_8 wnf[8];
    {
        const unsigned short* wn_g =
            w_hh + (long)(2 * HID + jt * 16 + fr) * HID + kbase + fk;
#pragma unroll
        for (int kk = 0; kk < 8; ++kk)
            wnf[kk] = *(const bf16_8*)(wn_g + (kk << 5));
    }

    const int j = jt * 16 + ec;
    float bhr = 0.f, bhz = 0.f, bhn = 0.f;
    float hold[4] = {0.f, 0.f, 0.f, 0.f};
    float gir[4], giz[4], gin[4];
    if (wave == 0) {
        bhr = b_hh[j];
        bhz = b_hh[HID + j];
        bhn = b_hh[2 * HID + j];
#pragma unroll
        for (int i = 0; i < 4; ++i)
            hold[i] = h0[(mt * 16 + er * 4 + i) * HID + j];
        // gi for step 0
        const float* gb = gi + (long)(mt * 16 + er * 4) * (3 * HID) + j;
#pragma unroll
        for (int i = 0; i < 4; ++i) {
            gir[i] = gb[(long)i * 3 * HID];
            giz[i] = gb[(long)i * 3 * HID + HID];
            gin[i] = gb[(long)i * 3 * HID + 2 * HID];
        }
    }

    const int sw = (fr & 7) << 3;  // element-index XOR for swizzled LDS reads

    __syncthreads();  // drain global_load_lds staging

    for (int s = 0; s < SEQ; ++s) {
        // ---- K-quarter MFMA: gh partials for this wave ----
        const unsigned short* aptr =
            hb + (long)s * BATCH * HID + (mt * 16 + fr) * HID + kbase + fk;
        f32x4 accr = (f32x4){0.f, 0.f, 0.f, 0.f};
        f32x4 accz = (f32x4){0.f, 0.f, 0.f, 0.f};
        f32x4 accn = (f32x4){0.f, 0.f, 0.f, 0.f};
#pragma unroll
        for (int kk = 0; kk < 8; ++kk) {
            const int kc = (kbase + (kk << 5) + fk) ^ sw;
            bf16_8 a = *(const bf16_8*)(aptr + (kk << 5));
            bf16_8 br = *(const bf16_8*)&Ws[fr * 1024 + kc];
            bf16_8 bz = *(const bf16_8*)&Ws[16384 + fr * 1024 + kc];
            accr = __builtin_amdgcn_mfma_f32_16x16x32_bf16(a, br, accr, 0, 0, 0);
            accz = __builtin_amdgcn_mfma_f32_16x16x32_bf16(a, bz, accz, 0, 0, 0);
            accn = __builtin_amdgcn_mfma_f32_16x16x32_bf16(a, wnf[kk], accn, 0, 0, 0);
        }

        if (wave != 0) {
            float* p = &Ps[(((wave - 1) * 3) * 64 + lane) * 4];
            *(f32x4*)(p) = accr;
            *(f32x4*)(p + 256) = accz;   // (+1 gate)*64 lanes*4
            *(f32x4*)(p + 512) = accn;
        }
        __syncthreads();  // partials visible to wave 0

        if (wave == 0) {
            // reduce 3 other waves' partials
#pragma unroll
            for (int w2 = 0; w2 < 3; ++w2) {
                const float* p = &Ps[((w2 * 3) * 64 + lane) * 4];
                accr += *(const f32x4*)(p);
                accz += *(const f32x4*)(p + 256);
                accn += *(const f32x4*)(p + 512);
            }

            unsigned short* hb_out = hb + (long)(s + 1) * BATCH * HID;
#pragma unroll
            for (int i = 0; i < 4; ++i) {
                const int b = mt * 16 + er * 4 + i;
                float ghr = accr[i] + bhr;
                float ghz = accz[i] + bhz;
                float ghn = accn[i] + bhn;
                float rg = 1.f / (1.f + __expf(-(gir[i] + ghr)));
                float zg = 1.f / (1.f + __expf(-(giz[i] + ghz)));
                float ng = tanhf(gin[i] + rg * ghn);
                float hn = (1.f - zg) * ng + zg * hold[i];
                hold[i] = hn;
                __hip_atomic_store(&hb_out[b * HID + j], f32_to_bf16_rne(hn),
                                   __ATOMIC_RELAXED, __HIP_MEMORY_SCOPE_AGENT);
            }

            if (s < SEQ - 1) {
                const unsigned ep = (unsigned)(s + 1);
                // release: h stores acknowledged at coherence point before arrive
                asm volatile("s_waitcnt vmcnt(0)" ::: "memory");
                if (lane == 0)
                    __hip_atomic_store(grp_slots + (jt << 4), ep,
                                       __ATOMIC_RELAXED, __HIP_MEMORY_SCOPE_AGENT);
                // prefetch next step's gi while polling
                {
                    const float* gb =
                        gi + (long)((s + 1) * BATCH + mt * 16 + er * 4) * (3 * HID) + j;
#pragma unroll
                    for (int i = 0; i < 4; ++i) {
                        gir[i] = gb[(long)i * 3 * HID];
                        giz[i] = gb[(long)i * 3 * HID + HID];
                        gin[i] = gb[(long)i * 3 * HID + 2 * HID];
                    }
                }
                // all-to-all poll: lane L watches slot of block (mt, jt=L)
                int spins = 0;
                for (;;) {
                    unsigned v = __hip_atomic_load(grp_slots + (lane << 4),
                                                   __ATOMIC_RELAXED,
                                                   __HIP_MEMORY_SCOPE_AGENT);
                    if (__all(v >= ep)) break;
                    if (++spins > 30000) break;  // safety valve: no container hang
                    __builtin_amdgcn_s_sleep(2);
                }
            }
        }
        __syncthreads();  // release waves 1..3 into the next step
    }
}

extern "C" void kernel_launch(void* const* d_in, const int* in_sizes, int n_in,
                              void* d_out, int out_size, void* d_ws, size_t ws_size,
                              hipStream_t stream) {
    const int* x = (const int*)d_in[0];
    const float* hidden = (const float*)d_in[1];
    const float* emb = (const float*)d_in[2];
    const float* w_ih = (const float*)d_in[3];
    const float* w_hh = (const float*)d_in[4];
    const float* b_ih = (const float*)d_in[5];
    const float* b_hh = (const float*)d_in[6];
    const float* w_out = (const float*)d_in[7];
    const float* b_out = (const float*)d_in[8];
    float* out = (float*)d_out;

    char* ws = (char*)d_ws;
    // workspace layout (all offsets 256B aligned)
    unsigned short* w_ih_bf  = (unsigned short*)(ws + 0);            //  3,145,728 B
    unsigned short* w_hh_bf  = (unsigned short*)(ws + 3145728);      //  6,291,456 B
    unsigned short* w_out_bf = (unsigned short*)(ws + 9437184);      // 65,536,000 B
    unsigned short* e_bf     = (unsigned short*)(ws + 74973184);     //  4,194,304 B
    float*          gi       = (float*)(ws + 79167488);              // 50,331,648 B
    unsigned*       bar      = (unsigned*)(ws + 129499136);          //     18,432 B
    unsigned short* hb       = (unsigned short*)(ws + 146538496);    //  8,519,680 B

    // 1. convert weights to bf16
    f32_to_bf16_vec<<<(3 * HID * EMB / 4 + 255) / 256, 256, 0, stream>>>(w_ih, w_ih_bf, 3 * HID * EMB / 4);
    f32_to_bf16_vec<<<(3 * HID * HID / 4 + 255) / 256, 256, 0, stream>>>(w_hh, w_hh_bf, 3 * HID * HID / 4);
    f32_to_bf16_vec<<<(VOCAB * HID / 4 + 255) / 256, 256, 0, stream>>>(w_out, w_out_bf, VOCAB * HID / 4);

    // 2. h0 -> hb[0]; zero barrier region
    init_h_kernel<<<BATCH * HID / 256, 256, 0, stream>>>(hidden, hb, bar);

    // 3. embedding gather + relu -> e_bf (4096, 512)
    embed_relu_kernel<<<SEQ * BATCH * EMB / 256, 256, 0, stream>>>(x, emb, e_bf);

    // 4. gi = e @ w_ih^T + b_ih : (4096, 3072), K=512
    {
        dim3 grid(3 * HID / 128, SEQ * BATCH / 128);
        gemm_bf16_nt<<<grid, 256, 0, stream>>>(e_bf, w_ih_bf, b_ih, gi,
                                               SEQ * BATCH, 3 * HID, EMB, 0);
    }

    // 5. all 64 GRU steps in ONE plain-launch persistent kernel
    gru_fused_kernel<<<256, 256, 0, stream>>>(w_hh_bf, gi, b_hh, hidden, hb, bar);

    // 6. logits = hs @ w_out^T + b_out, stored as (B, S, V)
    {
        dim3 grid(VOCAB / 128, SEQ * BATCH / 128);
        gemm_bf16_nt<<<grid, 256, 0, stream>>>(hb + BATCH * HID, w_out_bf, b_out, out,
                                               SEQ * BATCH, VOCAB, HID, 1);
    }
}